// Round 8
// baseline (465.752 us; speedup 1.0000x reference)
//
#include <hip/hip_runtime.h>
#include <hip/hip_bf16.h>

// B=4, T=2048, H=1024, NH=16, HD=64. Inputs FP32, output FP32 (proven R7).
// Pipeline (compute validated by R2-R6 equivalence; output dtype fixed):
//   [0] cast W_qkv, W_out -> bf16 ws
//   [1] qkv GEMM (x fp32 cast fused in A-staging):
//       q->q_ws[b*T+t][h*64+d], k->k_ws[b,h,t,d], v->v_ws[b,h,d,t]
//   [2] MFMA flash attention (causal, online softmax) -> ao_ws bf16
//   [3] out = ao @ W_out^T -> d_out as FP32

typedef unsigned short ushort_t;
typedef __attribute__((ext_vector_type(8))) short  s8v;
typedef __attribute__((ext_vector_type(4))) float  f4v;
typedef __attribute__((ext_vector_type(4))) unsigned int u4v;

__device__ inline ushort_t f2bf(float f) {
    unsigned u = __builtin_bit_cast(unsigned, f);
    u += 0x7fffu + ((u >> 16) & 1u);   // RNE
    return (ushort_t)(u >> 16);
}

__global__ __launch_bounds__(256) void cast_f32_bf16(
    const float* __restrict__ in, ushort_t* __restrict__ out, int n8)
{
    int i = blockIdx.x * 256 + threadIdx.x;
    if (i >= n8) return;
    const float* p = in + (size_t)i * 8;
    f4v a = *(const f4v*)p;
    f4v b = *(const f4v*)(p + 4);
    union { u4v v; ushort_t u[8]; } o;
    #pragma unroll
    for (int j = 0; j < 4; j++) { o.u[j] = f2bf(a[j]); o.u[j + 4] = f2bf(b[j]); }
    *(u4v*)(out + (size_t)i * 8) = o.v;
}

// ---------------------------------------------------------------------------
// GEMM C[M,N] = A[M,K]*B[N,K]^T, K=1024, bf16 MFMA, f32 acc.
// BM=BN=128, BK=32; 4 waves 2x2; 64x64 per wave (4x4 mfma 16x16x32).
// AFP32: A is fp32, cast to bf16 during LDS staging.
// MODE 0: scatter q/k/v (bf16). MODE 1: row-major FP32 store to of.
// ---------------------------------------------------------------------------
#define LDA 40   // 32+8 pad: rows 80B apart -> 16B aligned, free 2-way conflicts

template<int MODE, int AFP32>
__global__ __launch_bounds__(256) void gemm_nt(
    const void* __restrict__ Ain, const ushort_t* __restrict__ Bm,
    ushort_t* __restrict__ o0, ushort_t* __restrict__ o1, ushort_t* __restrict__ o2,
    float* __restrict__ of)
{
    __shared__ __align__(16) ushort_t As[128 * LDA];
    __shared__ __align__(16) ushort_t Bs[128 * LDA];

    const int tid  = threadIdx.x;
    const int m0   = blockIdx.x * 128;
    const int n0   = blockIdx.y * 128;
    const int wave = tid >> 6, lane = tid & 63;
    const int wr = wave >> 1, wc = wave & 1;
    const int lhi = lane >> 4, llo = lane & 15;

    f4v acc[4][4] = {};

    for (int k0 = 0; k0 < 1024; k0 += 32) {
        __syncthreads();
        #pragma unroll
        for (int p = 0; p < 2; p++) {
            int idx = (p * 256 + tid) * 8;
            int r = idx >> 5, c = idx & 31;
            if (AFP32) {
                const float* ap = (const float*)Ain + (size_t)(m0 + r) * 1024 + k0 + c;
                f4v x0 = *(const f4v*)ap;
                f4v x1 = *(const f4v*)(ap + 4);
                union { u4v v; ushort_t u[8]; } cv;
                #pragma unroll
                for (int j = 0; j < 4; j++) { cv.u[j] = f2bf(x0[j]); cv.u[j + 4] = f2bf(x1[j]); }
                *(u4v*)&As[r * LDA + c] = cv.v;
            } else {
                *(u4v*)&As[r * LDA + c] =
                    *(const u4v*)((const ushort_t*)Ain + (size_t)(m0 + r) * 1024 + k0 + c);
            }
            *(u4v*)&Bs[r * LDA + c] = *(const u4v*)(Bm + (size_t)(n0 + r) * 1024 + k0 + c);
        }
        __syncthreads();

        s8v a[4], b[4];
        #pragma unroll
        for (int i = 0; i < 4; i++)
            a[i] = *(const s8v*)&As[(wr * 64 + i * 16 + llo) * LDA + lhi * 8];
        #pragma unroll
        for (int i = 0; i < 4; i++)
            b[i] = *(const s8v*)&Bs[(wc * 64 + i * 16 + llo) * LDA + lhi * 8];
        #pragma unroll
        for (int i = 0; i < 4; i++)
            #pragma unroll
            for (int j = 0; j < 4; j++)
                acc[i][j] = __builtin_amdgcn_mfma_f32_16x16x32_bf16(a[i], b[j], acc[i][j], 0, 0, 0);
    }

    // acc[i][j] elem r -> (row = i*16 + lhi*4 + r, col = j*16 + llo)
    #pragma unroll
    for (int i = 0; i < 4; i++) {
        #pragma unroll
        for (int j = 0; j < 4; j++) {
            #pragma unroll
            for (int r = 0; r < 4; r++) {
                int m = m0 + wr * 64 + i * 16 + lhi * 4 + r;
                int n = n0 + wc * 64 + j * 16 + llo;
                if (MODE == 1) {
                    of[(size_t)m * 1024 + n] = acc[i][j][r];            // FP32 store
                } else {
                    ushort_t bv = f2bf(acc[i][j][r]);
                    int b  = m >> 11, t = m & 2047;
                    int which = n >> 10, hh = n & 1023;
                    int head = hh >> 6, d = hh & 63;
                    size_t bh = (size_t)(b * 16 + head);
                    if (which == 0)      o0[(size_t)m * 1024 + hh] = bv;       // Q [b*T+t][h*64+d]
                    else if (which == 1) o1[(bh * 2048 + t) * 64 + d] = bv;    // K [b,h,t,d]
                    else                 o2[(bh * 64 + d) * 2048 + t] = bv;    // V^T [b,h,d,t]
                }
            }
        }
    }
}

// ---------------------------------------------------------------------------
// MFMA flash attention, causal (R2-validated).
// ---------------------------------------------------------------------------
__global__ __launch_bounds__(256) void attn_kernel(
    const ushort_t* __restrict__ q_ws, const ushort_t* __restrict__ k_ws,
    const ushort_t* __restrict__ v_ws, ushort_t* __restrict__ ao_ws)
{
    const int qblk = blockIdx.x;
    const int bh   = blockIdx.y;
    const int q0   = qblk * 64;
    const int tid  = threadIdx.x;
    const int wave = tid >> 6, lane = tid & 63;
    const int lhi = lane >> 4, llo = lane & 15;
    const int b = bh >> 4, head = bh & 15;

    const ushort_t* Kb = k_ws + (size_t)bh * 2048 * 64;
    const ushort_t* Vb = v_ws + (size_t)bh * 64 * 2048;

    __shared__ __align__(16) ushort_t Ks [64 * 72];
    __shared__ __align__(16) ushort_t Vts[64 * 72];
    __shared__ __align__(16) ushort_t Ps [4][16 * 72];

    const int qrow = q0 + wave * 16 + llo;
    const ushort_t* Qp = q_ws + (size_t)(b * 2048 + qrow) * 1024 + head * 64;
    s8v qf0 = *(const s8v*)(Qp + lhi * 8);
    s8v qf1 = *(const s8v*)(Qp + 32 + lhi * 8);

    f4v o[4] = {};
    float mrow[4], lrow[4];
    #pragma unroll
    for (int r = 0; r < 4; r++) { mrow[r] = -1e30f; lrow[r] = 0.f; }

    const int ntiles = qblk + 1;
    for (int t = 0; t < ntiles; t++) {
        const int kk0 = t * 64;
        __syncthreads();
        #pragma unroll
        for (int p = 0; p < 2; p++) {
            int idx = (p * 256 + tid) * 8;
            int r = idx >> 6, c = idx & 63;
            *(u4v*)&Ks [r * 72 + c] = *(const u4v*)(Kb + (size_t)(kk0 + r) * 64 + c);
            *(u4v*)&Vts[r * 72 + c] = *(const u4v*)(Vb + (size_t)r * 2048 + kk0 + c);
        }
        __syncthreads();

        f4v s[4];
        #pragma unroll
        for (int c = 0; c < 4; c++) {
            f4v z = {};
            s8v b0 = *(const s8v*)&Ks[(c * 16 + llo) * 72 + lhi * 8];
            s8v b1 = *(const s8v*)&Ks[(c * 16 + llo) * 72 + 32 + lhi * 8];
            z = __builtin_amdgcn_mfma_f32_16x16x32_bf16(qf0, b0, z, 0, 0, 0);
            z = __builtin_amdgcn_mfma_f32_16x16x32_bf16(qf1, b1, z, 0, 0, 0);
            s[c] = z;
        }

        const int qg = q0 + wave * 16;
        float rmax[4] = {-1e30f, -1e30f, -1e30f, -1e30f};
        #pragma unroll
        for (int c = 0; c < 4; c++) {
            int kkg = kk0 + c * 16 + llo;
            #pragma unroll
            for (int r = 0; r < 4; r++) {
                int qq = qg + lhi * 4 + r;
                float v = s[c][r] * 0.125f;
                v = (kkg <= qq) ? v : -1e9f;
                s[c][r] = v;
                rmax[r] = fmaxf(rmax[r], v);
            }
        }
        #pragma unroll
        for (int off = 1; off < 16; off <<= 1)
            #pragma unroll
            for (int r = 0; r < 4; r++)
                rmax[r] = fmaxf(rmax[r], __shfl_xor(rmax[r], off, 64));

        float alpha[4], rsum[4] = {0.f, 0.f, 0.f, 0.f};
        #pragma unroll
        for (int r = 0; r < 4; r++) {
            float mnew = fmaxf(mrow[r], rmax[r]);
            alpha[r] = __expf(mrow[r] - mnew);
            mrow[r] = mnew;
        }
        #pragma unroll
        for (int c = 0; c < 4; c++) {
            #pragma unroll
            for (int r = 0; r < 4; r++) {
                float p = __expf(s[c][r] - mrow[r]);
                rsum[r] += p;
                Ps[wave][(lhi * 4 + r) * 72 + c * 16 + llo] = f2bf(p);
            }
        }
        #pragma unroll
        for (int off = 1; off < 16; off <<= 1)
            #pragma unroll
            for (int r = 0; r < 4; r++)
                rsum[r] += __shfl_xor(rsum[r], off, 64);
        #pragma unroll
        for (int r = 0; r < 4; r++) lrow[r] = lrow[r] * alpha[r] + rsum[r];
        #pragma unroll
        for (int cd = 0; cd < 4; cd++)
            #pragma unroll
            for (int r = 0; r < 4; r++) o[cd][r] *= alpha[r];

        __syncthreads();

        s8v pa0 = *(const s8v*)&Ps[wave][llo * 72 + lhi * 8];
        s8v pa1 = *(const s8v*)&Ps[wave][llo * 72 + 32 + lhi * 8];
        #pragma unroll
        for (int cd = 0; cd < 4; cd++) {
            s8v vb0 = *(const s8v*)&Vts[(cd * 16 + llo) * 72 + lhi * 8];
            s8v vb1 = *(const s8v*)&Vts[(cd * 16 + llo) * 72 + 32 + lhi * 8];
            o[cd] = __builtin_amdgcn_mfma_f32_16x16x32_bf16(pa0, vb0, o[cd], 0, 0, 0);
            o[cd] = __builtin_amdgcn_mfma_f32_16x16x32_bf16(pa1, vb1, o[cd], 0, 0, 0);
        }
    }

    #pragma unroll
    for (int cd = 0; cd < 4; cd++) {
        #pragma unroll
        for (int r = 0; r < 4; r++) {
            int qq = q0 + wave * 16 + lhi * 4 + r;
            int d  = cd * 16 + llo;
            float v = o[cd][r] / lrow[r];
            ao_ws[((size_t)(b * 2048 + qq)) * 1024 + head * 64 + d] = f2bf(v);
        }
    }
}

// ---------------------------------------------------------------------------
extern "C" void kernel_launch(void* const* d_in, const int* in_sizes, int n_in,
                              void* d_out, int out_size, void* d_ws, size_t ws_size,
                              hipStream_t stream) {
    const float* x    = (const float*)d_in[0];   // [4,2048,1024] fp32
    const float* wqkv = (const float*)d_in[1];   // [3072,1024]   fp32
    const float* wout = (const float*)d_in[2];   // [1024,1024]   fp32

    // ws (bf16 elems): wqkvb 3M | woutb 1M | q 8M | k 8M | v 8M | ao 8M = 72 MB
    ushort_t* wqkvb = (ushort_t*)d_ws;
    ushort_t* woutb = wqkvb + 3145728;
    ushort_t* q_ws  = woutb + 1048576;
    ushort_t* k_ws  = q_ws + 8388608;
    ushort_t* v_ws  = k_ws + 8388608;
    ushort_t* ao_ws = v_ws + 8388608;
    float*    out   = (float*)d_out;             // FP32 output (proven R7)

    cast_f32_bf16<<<1536, 256, 0, stream>>>(wqkv, wqkvb, 393216);
    cast_f32_bf16<<< 512, 256, 0, stream>>>(wout, woutb, 131072);
    // [1] QKV projection: M=8192, N=3072 (x cast fused in staging)
    gemm_nt<0, 1><<<dim3(64, 24), 256, 0, stream>>>(x, wqkvb, q_ws, k_ws, v_ws, nullptr);
    // [2] flash attention
    attn_kernel<<<dim3(32, 64), 256, 0, stream>>>(q_ws, k_ws, v_ws, ao_ws);
    // [3] output projection: M=8192, N=1024 -> fp32
    gemm_nt<1, 0><<<dim3(64, 8), 256, 0, stream>>>(ao_ws, woutb, nullptr, nullptr, nullptr, out);
}

// Round 9
// 450.764 us; speedup vs baseline: 1.0333x; 1.0333x over previous
//
#include <hip/hip_runtime.h>
#include <hip/hip_bf16.h>

// B=4, T=2048, H=1024, NH=16, HD=64. Inputs FP32, output FP32.
// R9: [a] GEMMs upgraded to m97 structure (global_load_lds width=16, unpadded
//     stride-32 LDS, x pre-cast to bf16). [b] attention restructured: q-tile
//     128/block (wave=32 rows), tile-iters halved, mask skipped on full
//     tiles, long blocks first, Ps stride 40 (conflict-free write/read).

typedef unsigned short ushort_t;
typedef __attribute__((ext_vector_type(8))) short  s8v;
typedef __attribute__((ext_vector_type(4))) float  f4v;
typedef __attribute__((ext_vector_type(4))) unsigned int u4v;

__device__ inline ushort_t f2bf(float f) {
    unsigned u = __builtin_bit_cast(unsigned, f);
    u += 0x7fffu + ((u >> 16) & 1u);   // RNE
    return (ushort_t)(u >> 16);
}

// async global->LDS, 16B per lane; LDS dest must be wave-uniform base + lane*16
__device__ inline void gload16(const ushort_t* g, ushort_t* l) {
    __builtin_amdgcn_global_load_lds(
        (const __attribute__((address_space(1))) unsigned int*)g,
        (__attribute__((address_space(3))) unsigned int*)l, 16, 0, 0);
}

__global__ __launch_bounds__(256) void cast_f32_bf16(
    const float* __restrict__ in, ushort_t* __restrict__ out, int n8)
{
    int i = blockIdx.x * 256 + threadIdx.x;
    if (i >= n8) return;
    const float* p = in + (size_t)i * 8;
    f4v a = *(const f4v*)p;
    f4v b = *(const f4v*)(p + 4);
    union { u4v v; ushort_t u[8]; } o;
    #pragma unroll
    for (int j = 0; j < 4; j++) { o.u[j] = f2bf(a[j]); o.u[j + 4] = f2bf(b[j]); }
    *(u4v*)(out + (size_t)i * 8) = o.v;
}

// ---------------------------------------------------------------------------
// GEMM C[M,N] = A[M,K]*B[N,K]^T, K=1024, bf16 MFMA, f32 acc. m97 structure:
// BM=BN=128, BK=32, unpadded LDS (stride 32), global_load_lds width 16.
// MODE 0: scatter q/k/v (bf16). MODE 1: row-major FP32 store.
// ---------------------------------------------------------------------------
template<int MODE>
__global__ __launch_bounds__(256) void gemm_nt(
    const ushort_t* __restrict__ A, const ushort_t* __restrict__ Bm,
    ushort_t* __restrict__ o0, ushort_t* __restrict__ o1, ushort_t* __restrict__ o2,
    float* __restrict__ of)
{
    __shared__ __align__(16) ushort_t As[4096];   // [128][32]
    __shared__ __align__(16) ushort_t Bs[4096];

    const int tid  = threadIdx.x;
    const int m0   = blockIdx.x * 128;
    const int n0   = blockIdx.y * 128;
    const int wave = tid >> 6, lane = tid & 63;
    const int wr = wave >> 1, wc = wave & 1;
    const int lhi = lane >> 4, llo = lane & 15;
    const int srow = lane >> 2, scol = (lane & 3) * 8;   // staging lane map

    f4v acc[4][4] = {};

    for (int k0 = 0; k0 < 1024; k0 += 32) {
        __syncthreads();
        #pragma unroll
        for (int p = 0; p < 2; p++) {
            int chunk = wave * 2 + p;                     // 0..7, 16 rows each
            int row = chunk * 16 + srow;
            gload16(A  + (size_t)(m0 + row) * 1024 + k0 + scol, &As[chunk * 512 + lane * 8]);
            gload16(Bm + (size_t)(n0 + row) * 1024 + k0 + scol, &Bs[chunk * 512 + lane * 8]);
        }
        __syncthreads();

        s8v a[4], b[4];
        #pragma unroll
        for (int i = 0; i < 4; i++)
            a[i] = *(const s8v*)&As[(wr * 64 + i * 16 + llo) * 32 + lhi * 8];
        #pragma unroll
        for (int i = 0; i < 4; i++)
            b[i] = *(const s8v*)&Bs[(wc * 64 + i * 16 + llo) * 32 + lhi * 8];
        #pragma unroll
        for (int i = 0; i < 4; i++)
            #pragma unroll
            for (int j = 0; j < 4; j++)
                acc[i][j] = __builtin_amdgcn_mfma_f32_16x16x32_bf16(a[i], b[j], acc[i][j], 0, 0, 0);
    }

    #pragma unroll
    for (int i = 0; i < 4; i++) {
        #pragma unroll
        for (int j = 0; j < 4; j++) {
            #pragma unroll
            for (int r = 0; r < 4; r++) {
                int m = m0 + wr * 64 + i * 16 + lhi * 4 + r;
                int n = n0 + wc * 64 + j * 16 + llo;
                if (MODE == 1) {
                    of[(size_t)m * 1024 + n] = acc[i][j][r];
                } else {
                    ushort_t bv = f2bf(acc[i][j][r]);
                    int b  = m >> 11, t = m & 2047;
                    int which = n >> 10, hh = n & 1023;
                    int head = hh >> 6, d = hh & 63;
                    size_t bh = (size_t)(b * 16 + head);
                    if (which == 0)      o0[(size_t)m * 1024 + hh] = bv;       // Q [b*T+t][h*64+d]
                    else if (which == 1) o1[(bh * 2048 + t) * 64 + d] = bv;    // K [b,h,t,d]
                    else                 o2[(bh * 64 + d) * 2048 + t] = bv;    // V^T [b,h,d,t]
                }
            }
        }
    }
}

// ---------------------------------------------------------------------------
// Flash attention, causal. Block = 128 q-rows x (b*h); wave w owns rows
// [q0+32w, q0+32w+32) as 2 x 16-row groups. KV tile 64 keys.
// LDS: K/V tiles in 32-col halves (stride 32, global_load_lds-compatible);
// Ps per-wave [2 halves][32 q][40] (conflict-free write & read).
// ---------------------------------------------------------------------------
__global__ __launch_bounds__(256) void attn_kernel(
    const ushort_t* __restrict__ q_ws, const ushort_t* __restrict__ k_ws,
    const ushort_t* __restrict__ v_ws, ushort_t* __restrict__ ao_ws)
{
    const int qt   = 15 - blockIdx.x;    // long blocks dispatched first
    const int bh   = blockIdx.y;
    const int q0   = qt * 128;
    const int tid  = threadIdx.x;
    const int wave = tid >> 6, lane = tid & 63;
    const int lhi = lane >> 4, llo = lane & 15;
    const int srow = lane >> 2, scol = (lane & 3) * 8;
    const int b = bh >> 4, head = bh & 15;

    const ushort_t* Kb = k_ws + (size_t)bh * 2048 * 64;
    const ushort_t* Vb = v_ws + (size_t)bh * 64 * 2048;   // [d][t]

    __shared__ __align__(16) ushort_t Ks [4096];          // [half][64 kk][32 d]
    __shared__ __align__(16) ushort_t Vts[4096];          // [half][64 d][32 kk]
    __shared__ __align__(16) ushort_t Ps [4][2560];       // [half][32 q][40]

    // Q fragments: 2 row-groups x 2 d-chunks
    s8v qf[2][2];
    #pragma unroll
    for (int g = 0; g < 2; g++) {
        int qrow = q0 + wave * 32 + g * 16 + llo;
        const ushort_t* Qp = q_ws + (size_t)(b * 2048 + qrow) * 1024 + head * 64;
        qf[g][0] = *(const s8v*)(Qp + lhi * 8);
        qf[g][1] = *(const s8v*)(Qp + 32 + lhi * 8);
    }

    f4v o[2][4] = {};
    float mrow[2][4], lrow[2][4];
    #pragma unroll
    for (int g = 0; g < 2; g++)
        #pragma unroll
        for (int r = 0; r < 4; r++) { mrow[g][r] = -1e30f; lrow[g][r] = 0.f; }

    const int ntiles = 2 * qt + 2;       // keys 0 .. q0+127
    for (int t = 0; t < ntiles; t++) {
        const int kk0 = t * 64;
        __syncthreads();                  // all waves done reading prev K/V
        #pragma unroll
        for (int j = 0; j < 4; j++) {
            int idx = wave * 4 + j;       // 16 issues: 8 K + 8 V
            int sub = idx & 7;
            int half = sub & 1, rb = sub >> 1;
            int row = rb * 16 + srow;
            if (idx < 8)
                gload16(Kb + (size_t)(kk0 + row) * 64 + half * 32 + scol,
                        &Ks[half * 2048 + rb * 512 + lane * 8]);
            else
                gload16(Vb + (size_t)row * 2048 + kk0 + half * 32 + scol,
                        &Vts[half * 2048 + rb * 512 + lane * 8]);
        }
        __syncthreads();                  // staging complete (drains vmcnt)

        const bool active = kk0 <= q0 + wave * 32 + 31;   // any unmasked key?
        const bool nomask = (kk0 + 63) <= (q0 + wave * 32);

        if (active) {
            s8v kb0[4], kb1[4];
            #pragma unroll
            for (int c = 0; c < 4; c++) {
                kb0[c] = *(const s8v*)&Ks[(c * 16 + llo) * 32 + lhi * 8];
                kb1[c] = *(const s8v*)&Ks[2048 + (c * 16 + llo) * 32 + lhi * 8];
            }
            #pragma unroll
            for (int g = 0; g < 2; g++) {
                f4v s[4];
                #pragma unroll
                for (int c = 0; c < 4; c++) {
                    f4v z = {};
                    z = __builtin_amdgcn_mfma_f32_16x16x32_bf16(qf[g][0], kb0[c], z, 0, 0, 0);
                    z = __builtin_amdgcn_mfma_f32_16x16x32_bf16(qf[g][1], kb1[c], z, 0, 0, 0);
                    s[c] = z;
                }
                const int qg = q0 + wave * 32 + g * 16;
                float rmax[4] = {-1e30f, -1e30f, -1e30f, -1e30f};
                #pragma unroll
                for (int c = 0; c < 4; c++) {
                    int kkg = kk0 + c * 16 + llo;
                    #pragma unroll
                    for (int r = 0; r < 4; r++) {
                        float v = s[c][r] * 0.125f;
                        if (!nomask) v = (kkg <= qg + lhi * 4 + r) ? v : -1e9f;
                        s[c][r] = v;
                        rmax[r] = fmaxf(rmax[r], v);
                    }
                }
                #pragma unroll
                for (int off = 1; off < 16; off <<= 1)
                    #pragma unroll
                    for (int r = 0; r < 4; r++)
                        rmax[r] = fmaxf(rmax[r], __shfl_xor(rmax[r], off, 64));

                float alpha[4], rsum[4] = {0.f, 0.f, 0.f, 0.f};
                #pragma unroll
                for (int r = 0; r < 4; r++) {
                    float mnew = fmaxf(mrow[g][r], rmax[r]);
                    alpha[r] = __expf(mrow[g][r] - mnew);
                    mrow[g][r] = mnew;
                }
                #pragma unroll
                for (int c = 0; c < 4; c++) {
                    #pragma unroll
                    for (int r = 0; r < 4; r++) {
                        float p = __expf(s[c][r] - mrow[g][r]);
                        rsum[r] += p;
                        Ps[wave][(c >> 1) * 1280 + (g * 16 + lhi * 4 + r) * 40
                                 + (c & 1) * 16 + llo] = f2bf(p);
                    }
                }
                #pragma unroll
                for (int off = 1; off < 16; off <<= 1)
                    #pragma unroll
                    for (int r = 0; r < 4; r++)
                        rsum[r] += __shfl_xor(rsum[r], off, 64);
                #pragma unroll
                for (int r = 0; r < 4; r++)
                    lrow[g][r] = lrow[g][r] * alpha[r] + rsum[r];
                #pragma unroll
                for (int cd = 0; cd < 4; cd++)
                    #pragma unroll
                    for (int r = 0; r < 4; r++) o[g][cd][r] *= alpha[r];
            }
        }
        __syncthreads();                  // Ps write -> A-frag read visibility

        if (active) {
            s8v vb0[4], vb1[4];
            #pragma unroll
            for (int cd = 0; cd < 4; cd++) {
                vb0[cd] = *(const s8v*)&Vts[(cd * 16 + llo) * 32 + lhi * 8];
                vb1[cd] = *(const s8v*)&Vts[2048 + (cd * 16 + llo) * 32 + lhi * 8];
            }
            #pragma unroll
            for (int g = 0; g < 2; g++) {
                s8v pa0 = *(const s8v*)&Ps[wave][(g * 16 + llo) * 40 + lhi * 8];
                s8v pa1 = *(const s8v*)&Ps[wave][1280 + (g * 16 + llo) * 40 + lhi * 8];
                #pragma unroll
                for (int cd = 0; cd < 4; cd++) {
                    o[g][cd] = __builtin_amdgcn_mfma_f32_16x16x32_bf16(pa0, vb0[cd], o[g][cd], 0, 0, 0);
                    o[g][cd] = __builtin_amdgcn_mfma_f32_16x16x32_bf16(pa1, vb1[cd], o[g][cd], 0, 0, 0);
                }
            }
        }
    }

    #pragma unroll
    for (int g = 0; g < 2; g++)
        #pragma unroll
        for (int cd = 0; cd < 4; cd++)
            #pragma unroll
            for (int r = 0; r < 4; r++) {
                int qq = q0 + wave * 32 + g * 16 + lhi * 4 + r;
                int d  = cd * 16 + llo;
                ao_ws[((size_t)(b * 2048 + qq)) * 1024 + head * 64 + d] =
                    f2bf(o[g][cd][r] / lrow[g][r]);
            }
}

// ---------------------------------------------------------------------------
extern "C" void kernel_launch(void* const* d_in, const int* in_sizes, int n_in,
                              void* d_out, int out_size, void* d_ws, size_t ws_size,
                              hipStream_t stream) {
    const float* x    = (const float*)d_in[0];
    const float* wqkv = (const float*)d_in[1];
    const float* wout = (const float*)d_in[2];

    // ws (bf16 elems): wqkvb 3M | woutb 1M | xb 8M (reused as ao) | q 8M | k 8M | v 8M = 72 MB
    ushort_t* wqkvb = (ushort_t*)d_ws;
    ushort_t* woutb = wqkvb + 3145728;
    ushort_t* xb    = woutb + 1048576;
    ushort_t* q_ws  = xb + 8388608;
    ushort_t* k_ws  = q_ws + 8388608;
    ushort_t* v_ws  = k_ws + 8388608;
    ushort_t* ao_ws = xb;                 // xb dead after QKV GEMM
    float*    out   = (float*)d_out;

    cast_f32_bf16<<<4096, 256, 0, stream>>>(x,    xb,    1048576);
    cast_f32_bf16<<<1536, 256, 0, stream>>>(wqkv, wqkvb, 393216);
    cast_f32_bf16<<< 512, 256, 0, stream>>>(wout, woutb, 131072);
    gemm_nt<0><<<dim3(64, 24), 256, 0, stream>>>(xb, wqkvb, q_ws, k_ws, v_ws, nullptr);
    attn_kernel<<<dim3(16, 64), 256, 0, stream>>>(q_ws, k_ws, v_ws, ao_ws);
    gemm_nt<1><<<dim3(64, 8), 256, 0, stream>>>(ao_ws, woutb, nullptr, nullptr, nullptr, out);
}